// Round 5
// baseline (380.097 us; speedup 1.0000x reference)
//
#include <hip/hip_runtime.h>
#include <math.h>

#define NNODE 65536
#define NEDGE 1048576
#define NGRAPH 128
#define NPG 512
#define EPG 8192

typedef _Float16 f16x8 __attribute__((ext_vector_type(8)));
typedef _Float16 f16x4 __attribute__((ext_vector_type(4)));
typedef float f32x4 __attribute__((ext_vector_type(4)));

// ---- CSR build (block per graph) + init: alive, gate, dinv(layer1) ----

__global__ __launch_bounds__(512) void k_csr(const int* __restrict__ srcE, const int* __restrict__ dstE,
                                             int* __restrict__ rp, int* __restrict__ csr,
                                             float* __restrict__ gate, int* __restrict__ alive,
                                             float* __restrict__ dinv) {
    __shared__ int cnt[512];
    __shared__ int tmp[512];
    int g = blockIdx.x, t = threadIdx.x;
    int nd = g * NPG + t;
    cnt[t] = 0;
    gate[nd] = 1.f;
    alive[nd] = nd;
    __syncthreads();
    int ebase = g * EPG;
    int dl[16];
    for (int i = 0; i < 16; ++i) {
        int e = ebase + t + i * 512;
        int d = dstE[e] - g * NPG;
        dl[i] = d;
        atomicAdd(&cnt[d], 1);
    }
    __syncthreads();
    int v = cnt[t], incl = v;
    dinv[nd] = rsqrtf(1.f + (float)v);
    for (int off = 1; off < 512; off <<= 1) {
        tmp[t] = incl; __syncthreads();
        if (t >= off) incl += tmp[t - off];
        __syncthreads();
    }
    int excl = incl - v;
    rp[nd] = ebase + excl;
    if (g == NGRAPH - 1 && t == 511) rp[NNODE] = NEDGE;
    __syncthreads();
    cnt[t] = excl;
    __syncthreads();
    for (int i = 0; i < 16; ++i) {
        int e = ebase + t + i * 512;
        int pos = atomicAdd(&cnt[dl[i]], 1);
        csr[ebase + pos] = srcE[e];
    }
}

// ---- one-time: W (3 layers) -> fragment-ordered fp16 hi/lo ----
// frag layout: idx = ((nt*4 + ks)*64 + (quad*16 + nn))*8 + j ; nt=n>>4, nn=n&15, ks=k>>5, quad=(k&31)>>3, j=k&7

__global__ __launch_bounds__(256) void k_wconv(const float* __restrict__ W0, const float* __restrict__ W1,
                                               const float* __restrict__ W2, _Float16* __restrict__ wh,
                                               _Float16* __restrict__ wl) {
    int l = blockIdx.x >> 6;
    int e = (blockIdx.x & 63) * 256 + threadIdx.x;   // 0..16383
    const float* W = (l == 0) ? W0 : (l == 1) ? W1 : W2;
    int k = e >> 7, n = e & 127;
    float w = W[e];
    _Float16 hi = (_Float16)w;
    _Float16 lo = (_Float16)((w - (float)hi) * 2048.0f);
    int nt = n >> 4, nn = n & 15, ks = k >> 5, quad = (k & 31) >> 3, j = k & 7;
    int off = l * 16384 + ((nt * 4 + ks) * 64 + (quad * 16 + nn)) * 8 + j;
    wh[off] = hi;
    wl[off] = lo;
}

// ---- split-fp16 MFMA GEMM: h[alive rows] = (x*gate) @ W ----
// Block: 256 rows x 64 cols, 4 waves; wave = 64 rows (4 Mtiles) x 64 cols (4 Ntiles).
// h = AhBh + (AhBl + AlBh)/2048  (all products exact; error ~2^-22 relative)

__global__ __launch_bounds__(256, 2) void k_gemm(const float* __restrict__ x, const _Float16* __restrict__ wh,
                                                 const _Float16* __restrict__ wl, const float* __restrict__ gate,
                                                 const int* __restrict__ alive, float* __restrict__ h) {
    __shared__ _Float16 aHi[16384];  // [mtile16][ks2][lane64][8]  32 KB
    __shared__ _Float16 aLo[16384];  // 32 KB
    __shared__ _Float16 bHi[4096];   // [nt4][ks2][lane64][8]       8 KB
    __shared__ _Float16 bLo[4096];   // 8 KB
    int t = threadIdx.x;
    int lane = t & 63;
    int wv = t >> 6;
    int rowbase = blockIdx.x * 256;
    int colbase = blockIdx.y * 64;

    f32x4 ahh[4][4], amx[4][4];
    for (int a = 0; a < 4; ++a)
        for (int b = 0; b < 4; ++b) {
            ahh[a][b] = (f32x4){0.f, 0.f, 0.f, 0.f};
            amx[a][b] = (f32x4){0.f, 0.f, 0.f, 0.f};
        }

    for (int kh = 0; kh < 2; ++kh) {
        __syncthreads();
        // stage B frags (copy 16B segments from pre-converted global frag arrays)
        for (int pp = 0; pp < 2; ++pp) {
            int seg = t + pp * 256;            // 0..511 : [ntl2? no: ntl*2+ksl)*64+ln]
            int ntl = seg >> 7;
            int ksl = (seg >> 6) & 1;
            int ln = seg & 63;
            int gnt = (colbase >> 4) + ntl;
            int gks = kh * 2 + ksl;
            int goff = ((gnt * 4 + gks) * 64 + ln) * 8;
            ((uint4*)bHi)[seg] = *(const uint4*)(wh + goff);
            ((uint4*)bLo)[seg] = *(const uint4*)(wl + goff);
        }
        // stage A frags: 256 rows x 64 k, gated, f32 -> f16 hi/lo
        for (int pp = 0; pp < 16; ++pp) {
            int i = t + pp * 256;              // float4 id: 0..4095
            int r = i >> 4, q = i & 15;
            int node = alive[rowbase + r];
            float g = gate[node];
            float4 v = *(const float4*)(x + (size_t)node * 128 + kh * 64 + q * 4);
            v.x *= g; v.y *= g; v.z *= g; v.w *= g;
            _Float16 h0 = (_Float16)v.x, h1 = (_Float16)v.y, h2 = (_Float16)v.z, h3 = (_Float16)v.w;
            f16x4 hi4 = {h0, h1, h2, h3};
            f16x4 lo4 = {(_Float16)((v.x - (float)h0) * 2048.f), (_Float16)((v.y - (float)h1) * 2048.f),
                         (_Float16)((v.z - (float)h2) * 2048.f), (_Float16)((v.w - (float)h3) * 2048.f)};
            int mtile = r >> 4, m = r & 15, kstep = q >> 3, quad = (q >> 1) & 3, j0 = (q & 1) * 4;
            int off = ((mtile * 2 + kstep) * 64 + (quad * 16 + m)) * 8 + j0;
            *(f16x4*)(aHi + off) = hi4;
            *(f16x4*)(aLo + off) = lo4;
        }
        __syncthreads();

        f16x8 Ah[4][2], Al[4][2];
        for (int mi = 0; mi < 4; ++mi)
            for (int ks = 0; ks < 2; ++ks) {
                int mt = wv * 4 + mi;
                Ah[mi][ks] = *(const f16x8*)(aHi + ((mt * 2 + ks) * 64 + lane) * 8);
                Al[mi][ks] = *(const f16x8*)(aLo + ((mt * 2 + ks) * 64 + lane) * 8);
            }
        for (int nt = 0; nt < 4; ++nt) {
            f16x8 Bh0 = *(const f16x8*)(bHi + ((nt * 2 + 0) * 64 + lane) * 8);
            f16x8 Bh1 = *(const f16x8*)(bHi + ((nt * 2 + 1) * 64 + lane) * 8);
            f16x8 Bl0 = *(const f16x8*)(bLo + ((nt * 2 + 0) * 64 + lane) * 8);
            f16x8 Bl1 = *(const f16x8*)(bLo + ((nt * 2 + 1) * 64 + lane) * 8);
            for (int mi = 0; mi < 4; ++mi) {
                ahh[mi][nt] = __builtin_amdgcn_mfma_f32_16x16x32_f16(Ah[mi][0], Bh0, ahh[mi][nt], 0, 0, 0);
                ahh[mi][nt] = __builtin_amdgcn_mfma_f32_16x16x32_f16(Ah[mi][1], Bh1, ahh[mi][nt], 0, 0, 0);
                amx[mi][nt] = __builtin_amdgcn_mfma_f32_16x16x32_f16(Ah[mi][0], Bl0, amx[mi][nt], 0, 0, 0);
                amx[mi][nt] = __builtin_amdgcn_mfma_f32_16x16x32_f16(Al[mi][0], Bh0, amx[mi][nt], 0, 0, 0);
                amx[mi][nt] = __builtin_amdgcn_mfma_f32_16x16x32_f16(Ah[mi][1], Bl1, amx[mi][nt], 0, 0, 0);
                amx[mi][nt] = __builtin_amdgcn_mfma_f32_16x16x32_f16(Al[mi][1], Bh1, amx[mi][nt], 0, 0, 0);
            }
        }
    }

    // epilogue: C layout col=lane&15, row=quad*4+reg
    int quad = lane >> 4, nn = lane & 15;
    for (int mi = 0; mi < 4; ++mi)
        for (int nt = 0; nt < 4; ++nt) {
            f32x4 vh = ahh[mi][nt], vm = amx[mi][nt];
            for (int i = 0; i < 4; ++i) {
                int rl = (wv * 4 + mi) * 16 + quad * 4 + i;
                int node = alive[rowbase + rl];
                h[(size_t)node * 128 + colbase + nt * 16 + nn] = vh[i] + vm[i] * (1.f / 2048.f);
            }
        }
}

// ---------------- agg v3 (unchanged from R4) ----------------

__global__ __launch_bounds__(256) void k_agg(const float* __restrict__ h, const float* __restrict__ dinv,
                                             const int* __restrict__ rp, const int* __restrict__ csr,
                                             const int* __restrict__ alive, const float* __restrict__ bias,
                                             const float* __restrict__ p, float* __restrict__ out,
                                             float* __restrict__ score, int Kp) {
    __shared__ float2 nb[8][16];
    int t = threadIdx.x;
    int slot = t >> 5;
    int lane32 = t & 31;
    int half = slot & 1;
    int g = blockIdx.x & 127;
    int chunk = blockIdx.x >> 7;
    int idx = chunk * 8 + slot;

    int d = alive[g * Kp + idx];
    int jb = rp[d];
    int je = rp[d + 1];
    int deg = je - jb;

    int sid = 0; float wv = 0.f; bool livej = false;
    if (lane32 < 16 && lane32 < deg) {
        sid = csr[jb + lane32];
        wv = dinv[sid];
        livej = (wv != 0.f);
    }
    unsigned long long bal = __ballot(livej);
    unsigned hm = (unsigned)((bal >> (half * 32)) & 0xFFFFu);
    int cnt = __popc(hm);
    if (livej) {
        int pos = __popc(hm & ((1u << lane32) - 1));
        nb[slot][pos] = make_float2(wv, __int_as_float(sid));
    }

    float dvd = dinv[d];
    float4 hd = *(const float4*)(h + (size_t)d * 128 + lane32 * 4);
    float4 a0, a1;
    a0.x = dvd * hd.x; a0.y = dvd * hd.y; a0.z = dvd * hd.z; a0.w = dvd * hd.w;
    a1.x = 0.f; a1.y = 0.f; a1.z = 0.f; a1.w = 0.f;

    int j = 0;
    for (; j + 2 <= cnt; j += 2) {
        float2 n0 = nb[slot][j];
        float2 n1 = nb[slot][j + 1];
        int s0 = __float_as_int(n0.y);
        int s1 = __float_as_int(n1.y);
        float4 h0 = *(const float4*)(h + (size_t)s0 * 128 + lane32 * 4);
        float4 h1 = *(const float4*)(h + (size_t)s1 * 128 + lane32 * 4);
        a0.x = fmaf(n0.x, h0.x, a0.x); a0.y = fmaf(n0.x, h0.y, a0.y);
        a0.z = fmaf(n0.x, h0.z, a0.z); a0.w = fmaf(n0.x, h0.w, a0.w);
        a1.x = fmaf(n1.x, h1.x, a1.x); a1.y = fmaf(n1.x, h1.y, a1.y);
        a1.z = fmaf(n1.x, h1.z, a1.z); a1.w = fmaf(n1.x, h1.w, a1.w);
    }
    if (j < cnt) {
        float2 n0 = nb[slot][j];
        int s0 = __float_as_int(n0.y);
        float4 h0 = *(const float4*)(h + (size_t)s0 * 128 + lane32 * 4);
        a0.x = fmaf(n0.x, h0.x, a0.x); a0.y = fmaf(n0.x, h0.y, a0.y);
        a0.z = fmaf(n0.x, h0.z, a0.z); a0.w = fmaf(n0.x, h0.w, a0.w);
    }
    for (int j2 = jb + 16; j2 < je; ++j2) {
        int s2 = csr[j2];
        float w2 = dinv[s2];
        float4 h2 = *(const float4*)(h + (size_t)s2 * 128 + lane32 * 4);
        a0.x = fmaf(w2, h2.x, a0.x); a0.y = fmaf(w2, h2.y, a0.y);
        a0.z = fmaf(w2, h2.z, a0.z); a0.w = fmaf(w2, h2.w, a0.w);
    }

    float4 b4 = *(const float4*)(bias + lane32 * 4);
    float4 o;
    o.x = fmaxf(fmaf(dvd, a0.x + a1.x, b4.x), 0.f);
    o.y = fmaxf(fmaf(dvd, a0.y + a1.y, b4.y), 0.f);
    o.z = fmaxf(fmaf(dvd, a0.z + a1.z, b4.z), 0.f);
    o.w = fmaxf(fmaf(dvd, a0.w + a1.w, b4.w), 0.f);
    *(float4*)(out + (size_t)d * 128 + lane32 * 4) = o;

    float4 p4 = *(const float4*)(p + lane32 * 4);
    float ps = o.x * p4.x + o.y * p4.y + o.z * p4.z + o.w * p4.w;
    float q = p4.x * p4.x + p4.y * p4.y + p4.z * p4.z + p4.w * p4.w;
    for (int m = 16; m >= 1; m >>= 1) {
        ps += __shfl_xor(ps, m);
        q += __shfl_xor(q, m);
    }
    if (lane32 == 0) score[d] = 1.f / (1.f + expf(-ps * rsqrtf(q)));
}

// ---------------- fused: top-k + readout + next-layer dinv (unchanged) ----------------

__global__ __launch_bounds__(512) void k_pool(const float* __restrict__ xb, const float* __restrict__ score,
                                              float* __restrict__ gate, int* __restrict__ alive,
                                              float* __restrict__ hg, const int* __restrict__ rp,
                                              const int* __restrict__ csr, float* __restrict__ dinv,
                                              int K, int last) {
    __shared__ float s[512];
    __shared__ int ad[256];
    __shared__ float ag[256];
    __shared__ float red[1024];
    __shared__ int m_new[512];
    __shared__ int scnt;
    int t = threadIdx.x, g = blockIdx.x;
    int gbase = g * NPG;
    int d = gbase + t;

    float odv = dinv[d];
    int m = odv > 0.f;
    float sc = score[d];
    if (t == 0) scnt = 0;
    s[t] = m ? sc : -__builtin_inff();
    __syncthreads();
    for (int k2 = 2; k2 <= 512; k2 <<= 1)
        for (int j = k2 >> 1; j > 0; j >>= 1) {
            int ixj = t ^ j;
            if (ixj > t) {
                float a = s[t], bv = s[ixj];
                bool sw = ((t & k2) == 0) ? (a < bv) : (a > bv);
                if (sw) { s[t] = bv; s[ixj] = a; }
            }
            __syncthreads();
        }
    float thr = s[K - 1];
    int nm = (m && sc >= thr) ? 1 : 0;
    gate[d] = nm ? sc : 0.f;
    m_new[t] = nm;
    if (nm) {
        int pos = atomicAdd(&scnt, 1);
        if (pos < K) {
            alive[g * K + pos] = d;
            ad[pos] = d;
            ag[pos] = sc;
        }
    }
    __syncthreads();

    if (!last) {
        float nd = 0.f;
        if (nm) {
            int jb = rp[d], je = rp[d + 1];
            int sum = 0;
            for (int j = jb; j < je; ++j) sum += m_new[csr[j] - gbase];
            nd = rsqrtf(1.f + (float)sum);
        }
        dinv[d] = nd;
    }

    int f = t & 127, c = t >> 7;
    float mx = 0.f, sm = 0.f;
    for (int j = c; j < K; j += 16) {
        float v0 = xb[(size_t)ad[j] * 128 + f] * ag[j];
        float v1 = xb[(size_t)ad[j + 4] * 128 + f] * ag[j + 4];
        float v2 = xb[(size_t)ad[j + 8] * 128 + f] * ag[j + 8];
        float v3 = xb[(size_t)ad[j + 12] * 128 + f] * ag[j + 12];
        mx = fmaxf(fmaxf(fmaxf(mx, v0), fmaxf(v1, v2)), v3);
        sm += v0 + v1 + v2 + v3;
    }
    red[t] = mx; red[512 + t] = sm;
    __syncthreads();
    if (c == 0) {
        for (int cc = 1; cc < 4; ++cc) {
            mx = fmaxf(mx, red[cc * 128 + f]);
            sm += red[512 + cc * 128 + f];
        }
        hg[g * 256 + f] += mx;
        hg[g * 256 + 128 + f] += sm / (float)K;
    }
}

// ---------------- fused MLP head (unchanged) ----------------

__global__ __launch_bounds__(256) void k_mlp(const float* __restrict__ inp_c, const float* __restrict__ hg,
                                             const float* __restrict__ We, const float* __restrict__ Wa,
                                             const float* __restrict__ ba, const float* __restrict__ Wb,
                                             const float* __restrict__ bb, const float* __restrict__ Wc,
                                             float* __restrict__ out) {
    __shared__ float fus[320];
    __shared__ float h1[256];
    __shared__ float h2[128];
    int t = threadIdx.x, g = blockIdx.x;
    if (t < 64) {
        float a = 0.f;
        for (int j = 0; j < 64; ++j) a = fmaf(inp_c[g * 64 + j], We[j * 64 + t], a);
        fus[t] = fmaxf(a, 0.f);
    }
    fus[64 + t] = hg[g * 256 + t];
    __syncthreads();
    {
        float a = ba[t];
        for (int j = 0; j < 320; ++j) a = fmaf(fus[j], Wa[j * 256 + t], a);
        h1[t] = fmaxf(a, 0.f);
    }
    __syncthreads();
    if (t < 128) {
        float a = bb[t];
        for (int j = 0; j < 256; ++j) a = fmaf(h1[j], Wb[j * 128 + t], a);
        h2[t] = fmaxf(a, 0.f);
    }
    __syncthreads();
    if (t == 0) {
        float a = 0.f;
        for (int j = 0; j < 128; ++j) a = fmaf(h2[j], Wc[j], a);
        out[g] = a;
    }
}

// ---------------- launch ----------------

extern "C" void kernel_launch(void* const* d_in, const int* in_sizes, int n_in,
                              void* d_out, int out_size, void* d_ws, size_t ws_size,
                              hipStream_t stream) {
    (void)in_sizes; (void)n_in; (void)out_size; (void)ws_size;
    const float* x_in  = (const float*)d_in[0];
    const float* inp_c = (const float*)d_in[1];
    const int*   ei    = (const int*)d_in[2];
    const int* srcE = ei;
    const int* dstE = ei + NEDGE;
    const float* Wl[3] = {(const float*)d_in[4], (const float*)d_in[6], (const float*)d_in[8]};
    const float* bl[3] = {(const float*)d_in[5], (const float*)d_in[7], (const float*)d_in[9]};
    const float* Pl[3] = {(const float*)d_in[10], (const float*)d_in[11], (const float*)d_in[12]};
    const float* We = (const float*)d_in[13];
    const float* Wa = (const float*)d_in[14];
    const float* ba = (const float*)d_in[15];
    const float* Wb = (const float*)d_in[16];
    const float* bb = (const float*)d_in[17];
    const float* Wc = (const float*)d_in[18];
    float* out = (float*)d_out;

    char* w = (char*)d_ws;
    size_t off = 0;
    auto alloc = [&](size_t bytes) -> void* {
        void* p = w + off;
        off = (off + bytes + 255) & ~(size_t)255;
        return p;
    };
    int*   rp    = (int*)alloc((NNODE + 1) * 4);
    int*   csr   = (int*)alloc(NEDGE * 4);
    float* dinv  = (float*)alloc(NNODE * 4);
    float* gate  = (float*)alloc(NNODE * 4);
    float* score = (float*)alloc(NNODE * 4);
    int*   alive = (int*)alloc(NNODE * 4);
    float* hbuf  = (float*)alloc((size_t)NNODE * 128 * 4);
    float* xbuf  = (float*)alloc((size_t)NNODE * 128 * 4);
    float* hg    = (float*)alloc(NGRAPH * 256 * 4);
    _Float16* wfh = (_Float16*)alloc(3 * 16384 * 2);
    _Float16* wfl = (_Float16*)alloc(3 * 16384 * 2);

    hipMemsetAsync(hg, 0, NGRAPH * 256 * 4, stream);
    k_wconv<<<192, 256, 0, stream>>>(Wl[0], Wl[1], Wl[2], wfh, wfl);
    k_csr<<<NGRAPH, 512, 0, stream>>>(srcE, dstE, rp, csr, gate, alive, dinv);

    const int rows_in[3] = {65536, 32768, 16384};
    const int Ks[3] = {256, 128, 64};
    const int Kp[3] = {512, 256, 128};
    for (int l = 0; l < 3; ++l) {
        const float* xin = (l == 0) ? x_in : xbuf;
        k_gemm<<<dim3(rows_in[l] / 256, 2), 256, 0, stream>>>(xin, wfh + l * 16384, wfl + l * 16384,
                                                              gate, alive, hbuf);
        k_agg<<<rows_in[l] / 8, 256, 0, stream>>>(hbuf, dinv, rp, csr, alive, bl[l], Pl[l],
                                                  xbuf, score, Kp[l]);
        k_pool<<<NGRAPH, 512, 0, stream>>>(xbuf, score, gate, alive, hg,
                                           rp, csr, dinv, Ks[l], l == 2);
    }
    k_mlp<<<NGRAPH, 256, 0, stream>>>(inp_c, hg, We, Wa, ba, Wb, bb, Wc, out);
}

// Round 6
// 309.826 us; speedup vs baseline: 1.2268x; 1.2268x over previous
//
#include <hip/hip_runtime.h>
#include <math.h>

#define NNODE 65536
#define NEDGE 1048576
#define NGRAPH 128
#define NPG 512
#define EPG 8192

typedef _Float16 f16x8 __attribute__((ext_vector_type(8)));
typedef _Float16 f16x4 __attribute__((ext_vector_type(4)));
typedef float f32x4 __attribute__((ext_vector_type(4)));

// ---- CSR build (block per graph) + init: alive, gate, dinv(layer1) ----

__global__ __launch_bounds__(512) void k_csr(const int* __restrict__ srcE, const int* __restrict__ dstE,
                                             int* __restrict__ rp, int* __restrict__ csr,
                                             float* __restrict__ gate, int* __restrict__ alive,
                                             float* __restrict__ dinv) {
    __shared__ int cnt[512];
    __shared__ int tmp[512];
    int g = blockIdx.x, t = threadIdx.x;
    int nd = g * NPG + t;
    cnt[t] = 0;
    gate[nd] = 1.f;
    alive[nd] = nd;
    __syncthreads();
    int ebase = g * EPG;
    int dl[16];
    for (int i = 0; i < 16; ++i) {
        int e = ebase + t + i * 512;
        int d = dstE[e] - g * NPG;
        dl[i] = d;
        atomicAdd(&cnt[d], 1);
    }
    __syncthreads();
    int v = cnt[t], incl = v;
    dinv[nd] = rsqrtf(1.f + (float)v);
    for (int off = 1; off < 512; off <<= 1) {
        tmp[t] = incl; __syncthreads();
        if (t >= off) incl += tmp[t - off];
        __syncthreads();
    }
    int excl = incl - v;
    rp[nd] = ebase + excl;
    if (g == NGRAPH - 1 && t == 511) rp[NNODE] = NEDGE;
    __syncthreads();
    cnt[t] = excl;
    __syncthreads();
    for (int i = 0; i < 16; ++i) {
        int e = ebase + t + i * 512;
        int pos = atomicAdd(&cnt[dl[i]], 1);
        csr[ebase + pos] = srcE[e];
    }
}

// ---- one-time: W (3 layers) -> fragment-ordered fp16 hi/lo ----
// frag: idx = ((nt*4+ks)*64 + (quad*16+nn))*8 + j ; nt=n>>4, nn=n&15, ks=k>>5, quad=(k&31)>>3, j=k&7

__global__ __launch_bounds__(256) void k_wconv(const float* __restrict__ W0, const float* __restrict__ W1,
                                               const float* __restrict__ W2, _Float16* __restrict__ wh,
                                               _Float16* __restrict__ wl) {
    int l = blockIdx.x >> 6;
    int e = (blockIdx.x & 63) * 256 + threadIdx.x;   // 0..16383
    const float* W = (l == 0) ? W0 : (l == 1) ? W1 : W2;
    int k = e >> 7, n = e & 127;
    float w = W[e];
    _Float16 hi = (_Float16)w;
    _Float16 lo = (_Float16)((w - (float)hi) * 2048.0f);
    int nt = n >> 4, nn = n & 15, ks = k >> 5, quad = (k & 31) >> 3, j = k & 7;
    int off = l * 16384 + ((nt * 4 + ks) * 64 + (quad * 16 + nn)) * 8 + j;
    wh[off] = hi;
    wl[off] = lo;
}

// ---- split-fp16 MFMA GEMM v2: h[alive rows] = gate_row * (x_row @ W) ----
// Block: 128 rows x 128 cols (full N), 4 waves; wave = 32 rows (2 mt) x 128 cols (8 nt).
// A staged row-major f16 hi/lo with +8 f16 pad (conflict-free both sides); B frag-ordered.
// h = AhBh + (AhBl + AlBh)/2048 ; gate applied in epilogue (commutes with row scaling).

#define CVT8(hi8, lo8, a0, a1, a2, a3, a4, a5, a6, a7)                         \
    {                                                                           \
        _Float16 q0 = (_Float16)a0, q1 = (_Float16)a1, q2 = (_Float16)a2,       \
                 q3 = (_Float16)a3, q4 = (_Float16)a4, q5 = (_Float16)a5,       \
                 q6 = (_Float16)a6, q7 = (_Float16)a7;                          \
        hi8 = (f16x8){q0, q1, q2, q3, q4, q5, q6, q7};                          \
        lo8 = (f16x8){(_Float16)((a0 - (float)q0) * 2048.f),                    \
                      (_Float16)((a1 - (float)q1) * 2048.f),                    \
                      (_Float16)((a2 - (float)q2) * 2048.f),                    \
                      (_Float16)((a3 - (float)q3) * 2048.f),                    \
                      (_Float16)((a4 - (float)q4) * 2048.f),                    \
                      (_Float16)((a5 - (float)q5) * 2048.f),                    \
                      (_Float16)((a6 - (float)q6) * 2048.f),                    \
                      (_Float16)((a7 - (float)q7) * 2048.f)};                   \
    }

__global__ __launch_bounds__(256, 2) void k_gemm(const float* __restrict__ x0, const _Float16* __restrict__ xh,
                                                 const _Float16* __restrict__ xl, const _Float16* __restrict__ wh,
                                                 const _Float16* __restrict__ wl, const float* __restrict__ gate,
                                                 const int* __restrict__ alive, float* __restrict__ h,
                                                 int srcF32) {
    __shared__ _Float16 aH[128 * 72];   // row-major, 64 k per kh + 8 pad -> 18 KB
    __shared__ _Float16 aL[128 * 72];
    __shared__ _Float16 bH[8192];       // [nt*2+ksl][lane] 16B chunks -> 16 KB
    __shared__ _Float16 bL[8192];
    int t = threadIdx.x;
    int lane = t & 63;
    int wv = t >> 6;
    int quad = lane >> 4, mm = lane & 15;
    int rowbase = blockIdx.x * 128;

    f32x4 accH[2][8], accM[2][8];
    for (int a = 0; a < 2; ++a)
        for (int b = 0; b < 8; ++b) {
            accH[a][b] = (f32x4){0.f, 0.f, 0.f, 0.f};
            accM[a][b] = (f32x4){0.f, 0.f, 0.f, 0.f};
        }

    for (int kh = 0; kh < 2; ++kh) {
        if (kh) __syncthreads();
        // stage B (1024 16B chunks = 8 nt x 2 ksl x 64 lanes)
        for (int pp = 0; pp < 4; ++pp) {
            int seg = t + pp * 256;
            int nt = seg >> 7, ksl = (seg >> 6) & 1, ln = seg & 63;
            int goff = ((nt * 4 + kh * 2 + ksl) * 64 + ln) * 8;
            *(uint4*)(bH + seg * 8) = *(const uint4*)(wh + goff);
            *(uint4*)(bL + seg * 8) = *(const uint4*)(wl + goff);
        }
        // stage A: 128 rows x 64 k ; chunk = 8 k
        for (int pp = 0; pp < 4; ++pp) {
            int c = t + pp * 256;
            int r = c >> 3, ch = c & 7;
            int node = alive[rowbase + r];
            size_t src = (size_t)node * 128 + kh * 64 + ch * 8;
            f16x8 hi8, lo8;
            if (srcF32) {
                float4 v0 = *(const float4*)(x0 + src);
                float4 v1 = *(const float4*)(x0 + src + 4);
                CVT8(hi8, lo8, v0.x, v0.y, v0.z, v0.w, v1.x, v1.y, v1.z, v1.w);
            } else {
                hi8 = *(const f16x8*)(xh + src);
                lo8 = *(const f16x8*)(xl + src);
            }
            *(f16x8*)(aH + r * 72 + ch * 8) = hi8;
            *(f16x8*)(aL + r * 72 + ch * 8) = lo8;
        }
        __syncthreads();

        for (int ksl = 0; ksl < 2; ++ksl) {
            f16x8 Ah[2], Al[2];
            for (int mt = 0; mt < 2; ++mt) {
                int row = wv * 32 + mt * 16 + mm;
                Ah[mt] = *(const f16x8*)(aH + row * 72 + ksl * 32 + quad * 8);
                Al[mt] = *(const f16x8*)(aL + row * 72 + ksl * 32 + quad * 8);
            }
            for (int nt = 0; nt < 8; ++nt) {
                f16x8 Bh = *(const f16x8*)(bH + ((nt * 2 + ksl) * 64 + lane) * 8);
                f16x8 Bl = *(const f16x8*)(bL + ((nt * 2 + ksl) * 64 + lane) * 8);
                for (int mt = 0; mt < 2; ++mt) {
                    accH[mt][nt] = __builtin_amdgcn_mfma_f32_16x16x32_f16(Ah[mt], Bh, accH[mt][nt], 0, 0, 0);
                    accM[mt][nt] = __builtin_amdgcn_mfma_f32_16x16x32_f16(Ah[mt], Bl, accM[mt][nt], 0, 0, 0);
                    accM[mt][nt] = __builtin_amdgcn_mfma_f32_16x16x32_f16(Al[mt], Bh, accM[mt][nt], 0, 0, 0);
                }
            }
        }
    }

    // epilogue: C layout col=lane&15, row=quad*4+reg ; apply gate
    for (int mt = 0; mt < 2; ++mt)
        for (int i = 0; i < 4; ++i) {
            int rl = wv * 32 + mt * 16 + quad * 4 + i;
            int node = alive[rowbase + rl];
            float g = gate[node];
            float* hr = h + (size_t)node * 128 + mm;
            for (int nt = 0; nt < 8; ++nt)
                hr[nt * 16] = g * (accH[mt][nt][i] + accM[mt][nt][i] * (1.f / 2048.f));
        }
}

// ---------------- agg: half-wave per dst row, L2 gather; writes hi/lo f16 planes ----

__global__ __launch_bounds__(256) void k_agg(const float* __restrict__ h, const float* __restrict__ dinv,
                                             const int* __restrict__ rp, const int* __restrict__ csr,
                                             const int* __restrict__ alive, const float* __restrict__ bias,
                                             const float* __restrict__ p, _Float16* __restrict__ xh,
                                             _Float16* __restrict__ xl, float* __restrict__ score, int Kp) {
    __shared__ float2 nb[8][16];
    int t = threadIdx.x;
    int slot = t >> 5;
    int lane32 = t & 31;
    int half = slot & 1;
    int g = blockIdx.x & 127;
    int chunk = blockIdx.x >> 7;
    int idx = chunk * 8 + slot;

    int d = alive[g * Kp + idx];
    int jb = rp[d];
    int je = rp[d + 1];
    int deg = je - jb;

    int sid = 0; float wv = 0.f; bool livej = false;
    if (lane32 < 16 && lane32 < deg) {
        sid = csr[jb + lane32];
        wv = dinv[sid];
        livej = (wv != 0.f);
    }
    unsigned long long bal = __ballot(livej);
    unsigned hm = (unsigned)((bal >> (half * 32)) & 0xFFFFu);
    int cnt = __popc(hm);
    if (livej) {
        int pos = __popc(hm & ((1u << lane32) - 1));
        nb[slot][pos] = make_float2(wv, __int_as_float(sid));
    }

    float dvd = dinv[d];
    float4 hd = *(const float4*)(h + (size_t)d * 128 + lane32 * 4);
    float4 a0, a1;
    a0.x = dvd * hd.x; a0.y = dvd * hd.y; a0.z = dvd * hd.z; a0.w = dvd * hd.w;
    a1.x = 0.f; a1.y = 0.f; a1.z = 0.f; a1.w = 0.f;

    int j = 0;
    for (; j + 2 <= cnt; j += 2) {
        float2 n0 = nb[slot][j];
        float2 n1 = nb[slot][j + 1];
        int s0 = __float_as_int(n0.y);
        int s1 = __float_as_int(n1.y);
        float4 h0 = *(const float4*)(h + (size_t)s0 * 128 + lane32 * 4);
        float4 h1 = *(const float4*)(h + (size_t)s1 * 128 + lane32 * 4);
        a0.x = fmaf(n0.x, h0.x, a0.x); a0.y = fmaf(n0.x, h0.y, a0.y);
        a0.z = fmaf(n0.x, h0.z, a0.z); a0.w = fmaf(n0.x, h0.w, a0.w);
        a1.x = fmaf(n1.x, h1.x, a1.x); a1.y = fmaf(n1.x, h1.y, a1.y);
        a1.z = fmaf(n1.x, h1.z, a1.z); a1.w = fmaf(n1.x, h1.w, a1.w);
    }
    if (j < cnt) {
        float2 n0 = nb[slot][j];
        int s0 = __float_as_int(n0.y);
        float4 h0 = *(const float4*)(h + (size_t)s0 * 128 + lane32 * 4);
        a0.x = fmaf(n0.x, h0.x, a0.x); a0.y = fmaf(n0.x, h0.y, a0.y);
        a0.z = fmaf(n0.x, h0.z, a0.z); a0.w = fmaf(n0.x, h0.w, a0.w);
    }
    for (int j2 = jb + 16; j2 < je; ++j2) {
        int s2 = csr[j2];
        float w2 = dinv[s2];
        float4 h2 = *(const float4*)(h + (size_t)s2 * 128 + lane32 * 4);
        a0.x = fmaf(w2, h2.x, a0.x); a0.y = fmaf(w2, h2.y, a0.y);
        a0.z = fmaf(w2, h2.z, a0.z); a0.w = fmaf(w2, h2.w, a0.w);
    }

    float4 b4 = *(const float4*)(bias + lane32 * 4);
    float4 o;
    o.x = fmaxf(fmaf(dvd, a0.x + a1.x, b4.x), 0.f);
    o.y = fmaxf(fmaf(dvd, a0.y + a1.y, b4.y), 0.f);
    o.z = fmaxf(fmaf(dvd, a0.z + a1.z, b4.z), 0.f);
    o.w = fmaxf(fmaf(dvd, a0.w + a1.w, b4.w), 0.f);

    // write hi/lo split planes (next gemm consumes directly; pool reconstructs)
    _Float16 q0 = (_Float16)o.x, q1 = (_Float16)o.y, q2 = (_Float16)o.z, q3 = (_Float16)o.w;
    f16x4 oh = {q0, q1, q2, q3};
    f16x4 ol = {(_Float16)((o.x - (float)q0) * 2048.f), (_Float16)((o.y - (float)q1) * 2048.f),
                (_Float16)((o.z - (float)q2) * 2048.f), (_Float16)((o.w - (float)q3) * 2048.f)};
    *(f16x4*)(xh + (size_t)d * 128 + lane32 * 4) = oh;
    *(f16x4*)(xl + (size_t)d * 128 + lane32 * 4) = ol;

    float4 p4 = *(const float4*)(p + lane32 * 4);
    float ps = o.x * p4.x + o.y * p4.y + o.z * p4.z + o.w * p4.w;
    float q = p4.x * p4.x + p4.y * p4.y + p4.z * p4.z + p4.w * p4.w;
    for (int m = 16; m >= 1; m >>= 1) {
        ps += __shfl_xor(ps, m);
        q += __shfl_xor(q, m);
    }
    if (lane32 == 0) score[d] = 1.f / (1.f + expf(-ps * rsqrtf(q)));
}

// ---------------- fused: top-k + readout (hi/lo reconstruct) + next-layer dinv ----------------

__global__ __launch_bounds__(512) void k_pool(const _Float16* __restrict__ xh, const _Float16* __restrict__ xl,
                                              const float* __restrict__ score, float* __restrict__ gate,
                                              int* __restrict__ alive, float* __restrict__ hg,
                                              const int* __restrict__ rp, const int* __restrict__ csr,
                                              float* __restrict__ dinv, int K, int last) {
    __shared__ float s[512];
    __shared__ int ad[256];
    __shared__ float ag[256];
    __shared__ float red[1024];
    __shared__ int m_new[512];
    __shared__ int scnt;
    int t = threadIdx.x, g = blockIdx.x;
    int gbase = g * NPG;
    int d = gbase + t;

    float odv = dinv[d];
    int m = odv > 0.f;
    float sc = score[d];
    if (t == 0) scnt = 0;
    s[t] = m ? sc : -__builtin_inff();
    __syncthreads();
    for (int k2 = 2; k2 <= 512; k2 <<= 1)
        for (int j = k2 >> 1; j > 0; j >>= 1) {
            int ixj = t ^ j;
            if (ixj > t) {
                float a = s[t], bv = s[ixj];
                bool sw = ((t & k2) == 0) ? (a < bv) : (a > bv);
                if (sw) { s[t] = bv; s[ixj] = a; }
            }
            __syncthreads();
        }
    float thr = s[K - 1];
    int nm = (m && sc >= thr) ? 1 : 0;
    gate[d] = nm ? sc : 0.f;
    m_new[t] = nm;
    if (nm) {
        int pos = atomicAdd(&scnt, 1);
        if (pos < K) {
            alive[g * K + pos] = d;
            ad[pos] = d;
            ag[pos] = sc;
        }
    }
    __syncthreads();

    if (!last) {
        float nd = 0.f;
        if (nm) {
            int jb = rp[d], je = rp[d + 1];
            int sum = 0;
            for (int j = jb; j < je; ++j) sum += m_new[csr[j] - gbase];
            nd = rsqrtf(1.f + (float)sum);
        }
        dinv[d] = nd;
    }

    int f = t & 127, c = t >> 7;
    float mx = 0.f, sm = 0.f;
#define REC(node) ((float)xh[(size_t)(node)*128 + f] + (float)xl[(size_t)(node)*128 + f] * (1.f / 2048.f))
    for (int j = c; j < K; j += 16) {
        float v0 = REC(ad[j]) * ag[j];
        float v1 = REC(ad[j + 4]) * ag[j + 4];
        float v2 = REC(ad[j + 8]) * ag[j + 8];
        float v3 = REC(ad[j + 12]) * ag[j + 12];
        mx = fmaxf(fmaxf(fmaxf(mx, v0), fmaxf(v1, v2)), v3);
        sm += v0 + v1 + v2 + v3;
    }
#undef REC
    red[t] = mx; red[512 + t] = sm;
    __syncthreads();
    if (c == 0) {
        for (int cc = 1; cc < 4; ++cc) {
            mx = fmaxf(mx, red[cc * 128 + f]);
            sm += red[512 + cc * 128 + f];
        }
        hg[g * 256 + f] += mx;
        hg[g * 256 + 128 + f] += sm / (float)K;
    }
}

// ---------------- fused MLP head ----------------

__global__ __launch_bounds__(256) void k_mlp(const float* __restrict__ inp_c, const float* __restrict__ hg,
                                             const float* __restrict__ We, const float* __restrict__ Wa,
                                             const float* __restrict__ ba, const float* __restrict__ Wb,
                                             const float* __restrict__ bb, const float* __restrict__ Wc,
                                             float* __restrict__ out) {
    __shared__ float fus[320];
    __shared__ float h1[256];
    __shared__ float h2[128];
    int t = threadIdx.x, g = blockIdx.x;
    if (t < 64) {
        float a = 0.f;
        for (int j = 0; j < 64; ++j) a = fmaf(inp_c[g * 64 + j], We[j * 64 + t], a);
        fus[t] = fmaxf(a, 0.f);
    }
    fus[64 + t] = hg[g * 256 + t];
    __syncthreads();
    {
        float a = ba[t];
        for (int j = 0; j < 320; ++j) a = fmaf(fus[j], Wa[j * 256 + t], a);
        h1[t] = fmaxf(a, 0.f);
    }
    __syncthreads();
    if (t < 128) {
        float a = bb[t];
        for (int j = 0; j < 256; ++j) a = fmaf(h1[j], Wb[j * 128 + t], a);
        h2[t] = fmaxf(a, 0.f);
    }
    __syncthreads();
    if (t == 0) {
        float a = 0.f;
        for (int j = 0; j < 128; ++j) a = fmaf(h2[j], Wc[j], a);
        out[g] = a;
    }
}

// ---------------- launch ----------------

extern "C" void kernel_launch(void* const* d_in, const int* in_sizes, int n_in,
                              void* d_out, int out_size, void* d_ws, size_t ws_size,
                              hipStream_t stream) {
    (void)in_sizes; (void)n_in; (void)out_size; (void)ws_size;
    const float* x_in  = (const float*)d_in[0];
    const float* inp_c = (const float*)d_in[1];
    const int*   ei    = (const int*)d_in[2];
    const int* srcE = ei;
    const int* dstE = ei + NEDGE;
    const float* Wl[3] = {(const float*)d_in[4], (const float*)d_in[6], (const float*)d_in[8]};
    const float* bl[3] = {(const float*)d_in[5], (const float*)d_in[7], (const float*)d_in[9]};
    const float* Pl[3] = {(const float*)d_in[10], (const float*)d_in[11], (const float*)d_in[12]};
    const float* We = (const float*)d_in[13];
    const float* Wa = (const float*)d_in[14];
    const float* ba = (const float*)d_in[15];
    const float* Wb = (const float*)d_in[16];
    const float* bb = (const float*)d_in[17];
    const float* Wc = (const float*)d_in[18];
    float* out = (float*)d_out;

    char* w = (char*)d_ws;
    size_t off = 0;
    auto alloc = [&](size_t bytes) -> void* {
        void* p = w + off;
        off = (off + bytes + 255) & ~(size_t)255;
        return p;
    };
    int*   rp    = (int*)alloc((NNODE + 1) * 4);
    int*   csr   = (int*)alloc(NEDGE * 4);
    float* dinv  = (float*)alloc(NNODE * 4);
    float* gate  = (float*)alloc(NNODE * 4);
    float* score = (float*)alloc(NNODE * 4);
    int*   alive = (int*)alloc(NNODE * 4);
    float* hbuf  = (float*)alloc((size_t)NNODE * 128 * 4);
    _Float16* xh = (_Float16*)alloc((size_t)NNODE * 128 * 2);
    _Float16* xl = (_Float16*)alloc((size_t)NNODE * 128 * 2);
    float* hg    = (float*)alloc(NGRAPH * 256 * 4);
    _Float16* wfh = (_Float16*)alloc(3 * 16384 * 2);
    _Float16* wfl = (_Float16*)alloc(3 * 16384 * 2);

    hipMemsetAsync(hg, 0, NGRAPH * 256 * 4, stream);
    k_wconv<<<192, 256, 0, stream>>>(Wl[0], Wl[1], Wl[2], wfh, wfl);
    k_csr<<<NGRAPH, 512, 0, stream>>>(srcE, dstE, rp, csr, gate, alive, dinv);

    const int rows_in[3] = {65536, 32768, 16384};
    const int Ks[3] = {256, 128, 64};
    const int Kp[3] = {512, 256, 128};
    for (int l = 0; l < 3; ++l) {
        k_gemm<<<rows_in[l] / 128, 256, 0, stream>>>(x_in, xh, xl, wfh + l * 16384, wfl + l * 16384,
                                                     gate, alive, hbuf, l == 0);
        k_agg<<<rows_in[l] / 8, 256, 0, stream>>>(hbuf, dinv, rp, csr, alive, bl[l], Pl[l],
                                                  xh, xl, score, Kp[l]);
        k_pool<<<NGRAPH, 512, 0, stream>>>(xh, xl, score, gate, alive, hg,
                                           rp, csr, dinv, Ks[l], l == 2);
    }
    k_mlp<<<NGRAPH, 256, 0, stream>>>(inp_c, hg, We, Wa, ba, Wb, bb, Wc, out);
}

// Round 7
// 289.766 us; speedup vs baseline: 1.3117x; 1.0692x over previous
//
#include <hip/hip_runtime.h>
#include <math.h>

#define NNODE 65536
#define NEDGE 1048576
#define NGRAPH 128
#define NPG 512
#define EPG 8192

typedef _Float16 f16x8 __attribute__((ext_vector_type(8)));
typedef _Float16 f16x4 __attribute__((ext_vector_type(4)));
typedef float f32x4 __attribute__((ext_vector_type(4)));

// ---- CSR build (block per graph) + init: alive, gate, dinv(layer1) ----

__global__ __launch_bounds__(512) void k_csr(const int* __restrict__ srcE, const int* __restrict__ dstE,
                                             int* __restrict__ rp, int* __restrict__ csr,
                                             float* __restrict__ gate, int* __restrict__ alive,
                                             float* __restrict__ dinv) {
    __shared__ int cnt[512];
    __shared__ int tmp[512];
    int g = blockIdx.x, t = threadIdx.x;
    int nd = g * NPG + t;
    cnt[t] = 0;
    gate[nd] = 1.f;
    alive[nd] = nd;
    __syncthreads();
    int ebase = g * EPG;
    int dl[16];
    for (int i = 0; i < 16; ++i) {
        int e = ebase + t + i * 512;
        int d = dstE[e] - g * NPG;
        dl[i] = d;
        atomicAdd(&cnt[d], 1);
    }
    __syncthreads();
    int v = cnt[t], incl = v;
    dinv[nd] = rsqrtf(1.f + (float)v);
    for (int off = 1; off < 512; off <<= 1) {
        tmp[t] = incl; __syncthreads();
        if (t >= off) incl += tmp[t - off];
        __syncthreads();
    }
    int excl = incl - v;
    rp[nd] = ebase + excl;
    if (g == NGRAPH - 1 && t == 511) rp[NNODE] = NEDGE;
    __syncthreads();
    cnt[t] = excl;
    __syncthreads();
    for (int i = 0; i < 16; ++i) {
        int e = ebase + t + i * 512;
        int pos = atomicAdd(&cnt[dl[i]], 1);
        csr[ebase + pos] = srcE[e];
    }
}

// ---- one-time: W (3 layers) -> fragment-ordered fp16 hi/lo ----

__global__ __launch_bounds__(256) void k_wconv(const float* __restrict__ W0, const float* __restrict__ W1,
                                               const float* __restrict__ W2, _Float16* __restrict__ wh,
                                               _Float16* __restrict__ wl) {
    int l = blockIdx.x >> 6;
    int e = (blockIdx.x & 63) * 256 + threadIdx.x;
    const float* W = (l == 0) ? W0 : (l == 1) ? W1 : W2;
    int k = e >> 7, n = e & 127;
    float w = W[e];
    _Float16 hi = (_Float16)w;
    _Float16 lo = (_Float16)((w - (float)hi) * 2048.0f);
    int nt = n >> 4, nn = n & 15, ks = k >> 5, quad = (k & 31) >> 3, j = k & 7;
    int off = l * 16384 + ((nt * 4 + ks) * 64 + (quad * 16 + nn)) * 8 + j;
    wh[off] = hi;
    wl[off] = lo;
}

// ---- split-fp16 MFMA GEMM v2 (unchanged from R6) ----

#define CVT8(hi8, lo8, a0, a1, a2, a3, a4, a5, a6, a7)                         \
    {                                                                           \
        _Float16 q0 = (_Float16)a0, q1 = (_Float16)a1, q2 = (_Float16)a2,       \
                 q3 = (_Float16)a3, q4 = (_Float16)a4, q5 = (_Float16)a5,       \
                 q6 = (_Float16)a6, q7 = (_Float16)a7;                          \
        hi8 = (f16x8){q0, q1, q2, q3, q4, q5, q6, q7};                          \
        lo8 = (f16x8){(_Float16)((a0 - (float)q0) * 2048.f),                    \
                      (_Float16)((a1 - (float)q1) * 2048.f),                    \
                      (_Float16)((a2 - (float)q2) * 2048.f),                    \
                      (_Float16)((a3 - (float)q3) * 2048.f),                    \
                      (_Float16)((a4 - (float)q4) * 2048.f),                    \
                      (_Float16)((a5 - (float)q5) * 2048.f),                    \
                      (_Float16)((a6 - (float)q6) * 2048.f),                    \
                      (_Float16)((a7 - (float)q7) * 2048.f)};                   \
    }

__global__ __launch_bounds__(256, 2) void k_gemm(const float* __restrict__ x0, const _Float16* __restrict__ xh,
                                                 const _Float16* __restrict__ xl, const _Float16* __restrict__ wh,
                                                 const _Float16* __restrict__ wl, const float* __restrict__ gate,
                                                 const int* __restrict__ alive, float* __restrict__ h,
                                                 int srcF32) {
    __shared__ _Float16 aH[128 * 72];
    __shared__ _Float16 aL[128 * 72];
    __shared__ _Float16 bH[8192];
    __shared__ _Float16 bL[8192];
    int t = threadIdx.x;
    int lane = t & 63;
    int wv = t >> 6;
    int quad = lane >> 4, mm = lane & 15;
    int rowbase = blockIdx.x * 128;

    f32x4 accH[2][8], accM[2][8];
    for (int a = 0; a < 2; ++a)
        for (int b = 0; b < 8; ++b) {
            accH[a][b] = (f32x4){0.f, 0.f, 0.f, 0.f};
            accM[a][b] = (f32x4){0.f, 0.f, 0.f, 0.f};
        }

    for (int kh = 0; kh < 2; ++kh) {
        if (kh) __syncthreads();
        for (int pp = 0; pp < 4; ++pp) {
            int seg = t + pp * 256;
            int nt = seg >> 7, ksl = (seg >> 6) & 1, ln = seg & 63;
            int goff = ((nt * 4 + kh * 2 + ksl) * 64 + ln) * 8;
            *(uint4*)(bH + seg * 8) = *(const uint4*)(wh + goff);
            *(uint4*)(bL + seg * 8) = *(const uint4*)(wl + goff);
        }
        for (int pp = 0; pp < 4; ++pp) {
            int c = t + pp * 256;
            int r = c >> 3, ch = c & 7;
            int node = alive[rowbase + r];
            size_t src = (size_t)node * 128 + kh * 64 + ch * 8;
            f16x8 hi8, lo8;
            if (srcF32) {
                float4 v0 = *(const float4*)(x0 + src);
                float4 v1 = *(const float4*)(x0 + src + 4);
                CVT8(hi8, lo8, v0.x, v0.y, v0.z, v0.w, v1.x, v1.y, v1.z, v1.w);
            } else {
                hi8 = *(const f16x8*)(xh + src);
                lo8 = *(const f16x8*)(xl + src);
            }
            *(f16x8*)(aH + r * 72 + ch * 8) = hi8;
            *(f16x8*)(aL + r * 72 + ch * 8) = lo8;
        }
        __syncthreads();

        for (int ksl = 0; ksl < 2; ++ksl) {
            f16x8 Ah[2], Al[2];
            for (int mt = 0; mt < 2; ++mt) {
                int row = wv * 32 + mt * 16 + mm;
                Ah[mt] = *(const f16x8*)(aH + row * 72 + ksl * 32 + quad * 8);
                Al[mt] = *(const f16x8*)(aL + row * 72 + ksl * 32 + quad * 8);
            }
            for (int nt = 0; nt < 8; ++nt) {
                f16x8 Bh = *(const f16x8*)(bH + ((nt * 2 + ksl) * 64 + lane) * 8);
                f16x8 Bl = *(const f16x8*)(bL + ((nt * 2 + ksl) * 64 + lane) * 8);
                for (int mt = 0; mt < 2; ++mt) {
                    accH[mt][nt] = __builtin_amdgcn_mfma_f32_16x16x32_f16(Ah[mt], Bh, accH[mt][nt], 0, 0, 0);
                    accM[mt][nt] = __builtin_amdgcn_mfma_f32_16x16x32_f16(Ah[mt], Bl, accM[mt][nt], 0, 0, 0);
                    accM[mt][nt] = __builtin_amdgcn_mfma_f32_16x16x32_f16(Al[mt], Bh, accM[mt][nt], 0, 0, 0);
                }
            }
        }
    }

    for (int mt = 0; mt < 2; ++mt)
        for (int i = 0; i < 4; ++i) {
            int rl = wv * 32 + mt * 16 + quad * 4 + i;
            int node = alive[rowbase + rl];
            float g = gate[node];
            float* hr = h + (size_t)node * 128 + mm;
            for (int nt = 0; nt < 8; ++nt)
                hr[nt * 16] = g * (accH[mt][nt][i] + accM[mt][nt][i] * (1.f / 2048.f));
        }
}

// ---- agg v4: half-wave per dst; 32-neighbor prefetch+compaction; 4x-unrolled gather ----
// deg is Poisson(16): P(deg>16)=47% -> 16-slot prefetch (R4/R6) serialized half the rows.

__global__ __launch_bounds__(256) void k_agg(const float* __restrict__ h, const float* __restrict__ dinv,
                                             const int* __restrict__ rp, const int* __restrict__ csr,
                                             const int* __restrict__ alive, const float* __restrict__ bias,
                                             const float* __restrict__ p, _Float16* __restrict__ xh,
                                             _Float16* __restrict__ xl, float* __restrict__ score, int Kp) {
    __shared__ float2 nb[8][32];
    int t = threadIdx.x;
    int slot = t >> 5;
    int lane32 = t & 31;
    int half = slot & 1;
    int g = blockIdx.x & 127;
    int chunk = blockIdx.x >> 7;
    int idx = chunk * 8 + slot;

    int d = alive[g * Kp + idx];
    int jb = rp[d];
    int je = rp[d + 1];
    int deg = je - jb;

    int sid = 0; float wv = 0.f; bool livej = false;
    if (lane32 < deg) {
        sid = csr[jb + lane32];
        wv = dinv[sid];
        livej = (wv != 0.f);
    }
    unsigned long long bal = __ballot(livej);
    unsigned hm = (unsigned)(bal >> (half * 32));
    int cnt = __popc(hm);
    if (livej) {
        int pos = __popc(hm & ((1u << lane32) - 1));
        nb[slot][pos] = make_float2(wv, __int_as_float(sid));
    }
    // producer half-wave == consumer half-wave: wave-synchronous, no barrier

    float dvd = dinv[d];
    float4 hd = *(const float4*)(h + (size_t)d * 128 + lane32 * 4);
    float4 a0, a1, a2, a3;
    a0.x = dvd * hd.x; a0.y = dvd * hd.y; a0.z = dvd * hd.z; a0.w = dvd * hd.w;
    a1 = make_float4(0.f, 0.f, 0.f, 0.f);
    a2 = a1; a3 = a1;

    int j = 0;
    for (; j + 4 <= cnt; j += 4) {
        float2 n0 = nb[slot][j];
        float2 n1 = nb[slot][j + 1];
        float2 n2 = nb[slot][j + 2];
        float2 n3 = nb[slot][j + 3];
        float4 h0 = *(const float4*)(h + (size_t)__float_as_int(n0.y) * 128 + lane32 * 4);
        float4 h1 = *(const float4*)(h + (size_t)__float_as_int(n1.y) * 128 + lane32 * 4);
        float4 h2 = *(const float4*)(h + (size_t)__float_as_int(n2.y) * 128 + lane32 * 4);
        float4 h3 = *(const float4*)(h + (size_t)__float_as_int(n3.y) * 128 + lane32 * 4);
        a0.x = fmaf(n0.x, h0.x, a0.x); a0.y = fmaf(n0.x, h0.y, a0.y);
        a0.z = fmaf(n0.x, h0.z, a0.z); a0.w = fmaf(n0.x, h0.w, a0.w);
        a1.x = fmaf(n1.x, h1.x, a1.x); a1.y = fmaf(n1.x, h1.y, a1.y);
        a1.z = fmaf(n1.x, h1.z, a1.z); a1.w = fmaf(n1.x, h1.w, a1.w);
        a2.x = fmaf(n2.x, h2.x, a2.x); a2.y = fmaf(n2.x, h2.y, a2.y);
        a2.z = fmaf(n2.x, h2.z, a2.z); a2.w = fmaf(n2.x, h2.w, a2.w);
        a3.x = fmaf(n3.x, h3.x, a3.x); a3.y = fmaf(n3.x, h3.y, a3.y);
        a3.z = fmaf(n3.x, h3.z, a3.z); a3.w = fmaf(n3.x, h3.w, a3.w);
    }
    for (; j < cnt; ++j) {
        float2 n0 = nb[slot][j];
        float4 h0 = *(const float4*)(h + (size_t)__float_as_int(n0.y) * 128 + lane32 * 4);
        a0.x = fmaf(n0.x, h0.x, a0.x); a0.y = fmaf(n0.x, h0.y, a0.y);
        a0.z = fmaf(n0.x, h0.z, a0.z); a0.w = fmaf(n0.x, h0.w, a0.w);
    }
    for (int j2 = jb + 32; j2 < je; ++j2) {   // deg>32: ~1e-4 of dsts
        int s2 = csr[j2];
        float w2 = dinv[s2];
        float4 h2 = *(const float4*)(h + (size_t)s2 * 128 + lane32 * 4);
        a0.x = fmaf(w2, h2.x, a0.x); a0.y = fmaf(w2, h2.y, a0.y);
        a0.z = fmaf(w2, h2.z, a0.z); a0.w = fmaf(w2, h2.w, a0.w);
    }

    float4 b4 = *(const float4*)(bias + lane32 * 4);
    float4 o;
    o.x = fmaxf(fmaf(dvd, a0.x + a1.x + a2.x + a3.x, b4.x), 0.f);
    o.y = fmaxf(fmaf(dvd, a0.y + a1.y + a2.y + a3.y, b4.y), 0.f);
    o.z = fmaxf(fmaf(dvd, a0.z + a1.z + a2.z + a3.z, b4.z), 0.f);
    o.w = fmaxf(fmaf(dvd, a0.w + a1.w + a2.w + a3.w, b4.w), 0.f);

    _Float16 q0 = (_Float16)o.x, q1 = (_Float16)o.y, q2 = (_Float16)o.z, q3 = (_Float16)o.w;
    f16x4 oh = {q0, q1, q2, q3};
    f16x4 ol = {(_Float16)((o.x - (float)q0) * 2048.f), (_Float16)((o.y - (float)q1) * 2048.f),
                (_Float16)((o.z - (float)q2) * 2048.f), (_Float16)((o.w - (float)q3) * 2048.f)};
    *(f16x4*)(xh + (size_t)d * 128 + lane32 * 4) = oh;
    *(f16x4*)(xl + (size_t)d * 128 + lane32 * 4) = ol;

    float4 p4 = *(const float4*)(p + lane32 * 4);
    float ps = o.x * p4.x + o.y * p4.y + o.z * p4.z + o.w * p4.w;
    float q = p4.x * p4.x + p4.y * p4.y + p4.z * p4.z + p4.w * p4.w;
    for (int m = 16; m >= 1; m >>= 1) {
        ps += __shfl_xor(ps, m);
        q += __shfl_xor(q, m);
    }
    if (lane32 == 0) score[d] = 1.f / (1.f + expf(-ps * rsqrtf(q)));
}

// ---- pool v2: radix-select top-k (histogram of score bits) + readout + next dinv ----

__global__ __launch_bounds__(512) void k_pool(const _Float16* __restrict__ xh, const _Float16* __restrict__ xl,
                                              const float* __restrict__ score, float* __restrict__ gate,
                                              int* __restrict__ alive, float* __restrict__ hg,
                                              const int* __restrict__ rp, const int* __restrict__ csr,
                                              float* __restrict__ dinv, int K, int last) {
    __shared__ unsigned hist[1024];
    __shared__ unsigned wsum[8];
    __shared__ float cand[512];
    __shared__ int ad[256];
    __shared__ float ag[256];
    __shared__ float red[1024];
    __shared__ int m_new[512];
    __shared__ int scnt;
    __shared__ unsigned ccnt;
    __shared__ unsigned tbb, tbab;
    __shared__ float thrS;
    int t = threadIdx.x, g = blockIdx.x;
    int gbase = g * NPG;
    int d = gbase + t;

    float odv = dinv[d];
    int m = odv > 0.f;
    float sc = score[d];
    // positive floats are order-isomorphic to their bit patterns; dead -> bucket 0
    unsigned bits = m ? __float_as_uint(sc) : 0u;
    unsigned bucket = bits >> 21;    // <= 508 for sc <= 1.0
    hist[t] = 0; hist[t + 512] = 0;
    if (t == 0) { scnt = 0; ccnt = 0; }
    __syncthreads();
    atomicAdd(&hist[bucket], 1u);
    __syncthreads();
    // suffix-sum (descending buckets): thread t owns reversed pair (1023-2t, 1022-2t)
    unsigned a0 = hist[1023 - 2 * t];
    unsigned a1 = hist[1022 - 2 * t];
    unsigned pair = a0 + a1;
    unsigned v = pair;
    for (int o = 1; o < 64; o <<= 1) {
        unsigned n = __shfl_up(v, o);
        if ((t & 63) >= o) v += n;
    }
    if ((t & 63) == 63) wsum[t >> 6] = v;
    __syncthreads();
    if (t == 0) {
        unsigned run = 0;
        for (int i = 0; i < 8; ++i) { unsigned x = wsum[i]; wsum[i] = run; run += x; }
    }
    __syncthreads();
    unsigned incl = v + wsum[t >> 6];
    unsigned excl = incl - pair;
    unsigned uK = (unsigned)K;
    if (excl < uK && excl + a0 >= uK) { tbb = 1023 - 2 * t; tbab = excl; }
    else if (excl + a0 < uK && incl >= uK) { tbb = 1022 - 2 * t; tbab = excl + a0; }
    __syncthreads();
    unsigned bsel = tbb;
    unsigned r = uK - tbab;                      // 1-indexed rank inside bucket
    if (m && bucket == bsel) {
        unsigned pos = atomicAdd(&ccnt, 1u);
        cand[pos] = sc;
    }
    __syncthreads();
    unsigned c = ccnt;
    if (t < (int)c) {
        float vv = cand[t];
        unsigned gt = 0;
        for (unsigned i = 0; i < c; ++i) gt += (cand[i] > vv) ? 1u : 0u;
        if (gt == r - 1) thrS = vv;
    }
    __syncthreads();
    float thr = thrS;

    int nm = (m && sc >= thr) ? 1 : 0;
    gate[d] = nm ? sc : 0.f;
    m_new[t] = nm;
    if (nm) {
        int pos = atomicAdd(&scnt, 1);
        if (pos < K) {
            alive[g * K + pos] = d;
            ad[pos] = d;
            ag[pos] = sc;
        }
    }
    __syncthreads();

    if (!last) {
        float nd = 0.f;
        if (nm) {
            int jb = rp[d], je = rp[d + 1];
            int sum = 0;
            for (int j = jb; j < je; ++j) sum += m_new[csr[j] - gbase];
            nd = rsqrtf(1.f + (float)sum);
        }
        dinv[d] = nd;
    }

    int f = t & 127, c2 = t >> 7;
    float mx = 0.f, sm = 0.f;
#define REC(node) ((float)xh[(size_t)(node)*128 + f] + (float)xl[(size_t)(node)*128 + f] * (1.f / 2048.f))
    for (int j = c2; j < K; j += 16) {
        float v0 = REC(ad[j]) * ag[j];
        float v1 = REC(ad[j + 4]) * ag[j + 4];
        float v2 = REC(ad[j + 8]) * ag[j + 8];
        float v3 = REC(ad[j + 12]) * ag[j + 12];
        mx = fmaxf(fmaxf(fmaxf(mx, v0), fmaxf(v1, v2)), v3);
        sm += v0 + v1 + v2 + v3;
    }
#undef REC
    red[t] = mx; red[512 + t] = sm;
    __syncthreads();
    if (c2 == 0) {
        for (int cc = 1; cc < 4; ++cc) {
            mx = fmaxf(mx, red[cc * 128 + f]);
            sm += red[512 + cc * 128 + f];
        }
        hg[g * 256 + f] += mx;
        hg[g * 256 + 128 + f] += sm / (float)K;
    }
}

// ---------------- fused MLP head ----------------

__global__ __launch_bounds__(256) void k_mlp(const float* __restrict__ inp_c, const float* __restrict__ hg,
                                             const float* __restrict__ We, const float* __restrict__ Wa,
                                             const float* __restrict__ ba, const float* __restrict__ Wb,
                                             const float* __restrict__ bb, const float* __restrict__ Wc,
                                             float* __restrict__ out) {
    __shared__ float fus[320];
    __shared__ float h1[256];
    __shared__ float h2[128];
    int t = threadIdx.x, g = blockIdx.x;
    if (t < 64) {
        float a = 0.f;
        for (int j = 0; j < 64; ++j) a = fmaf(inp_c[g * 64 + j], We[j * 64 + t], a);
        fus[t] = fmaxf(a, 0.f);
    }
    fus[64 + t] = hg[g * 256 + t];
    __syncthreads();
    {
        float a = ba[t];
        for (int j = 0; j < 320; ++j) a = fmaf(fus[j], Wa[j * 256 + t], a);
        h1[t] = fmaxf(a, 0.f);
    }
    __syncthreads();
    if (t < 128) {
        float a = bb[t];
        for (int j = 0; j < 256; ++j) a = fmaf(h1[j], Wb[j * 128 + t], a);
        h2[t] = fmaxf(a, 0.f);
    }
    __syncthreads();
    if (t == 0) {
        float a = 0.f;
        for (int j = 0; j < 128; ++j) a = fmaf(h2[j], Wc[j], a);
        out[g] = a;
    }
}

// ---------------- launch ----------------

extern "C" void kernel_launch(void* const* d_in, const int* in_sizes, int n_in,
                              void* d_out, int out_size, void* d_ws, size_t ws_size,
                              hipStream_t stream) {
    (void)in_sizes; (void)n_in; (void)out_size; (void)ws_size;
    const float* x_in  = (const float*)d_in[0];
    const float* inp_c = (const float*)d_in[1];
    const int*   ei    = (const int*)d_in[2];
    const int* srcE = ei;
    const int* dstE = ei + NEDGE;
    const float* Wl[3] = {(const float*)d_in[4], (const float*)d_in[6], (const float*)d_in[8]};
    const float* bl[3] = {(const float*)d_in[5], (const float*)d_in[7], (const float*)d_in[9]};
    const float* Pl[3] = {(const float*)d_in[10], (const float*)d_in[11], (const float*)d_in[12]};
    const float* We = (const float*)d_in[13];
    const float* Wa = (const float*)d_in[14];
    const float* ba = (const float*)d_in[15];
    const float* Wb = (const float*)d_in[16];
    const float* bb = (const float*)d_in[17];
    const float* Wc = (const float*)d_in[18];
    float* out = (float*)d_out;

    char* w = (char*)d_ws;
    size_t off = 0;
    auto alloc = [&](size_t bytes) -> void* {
        void* p = w + off;
        off = (off + bytes + 255) & ~(size_t)255;
        return p;
    };
    int*   rp    = (int*)alloc((NNODE + 1) * 4);
    int*   csr   = (int*)alloc(NEDGE * 4);
    float* dinv  = (float*)alloc(NNODE * 4);
    float* gate  = (float*)alloc(NNODE * 4);
    float* score = (float*)alloc(NNODE * 4);
    int*   alive = (int*)alloc(NNODE * 4);
    float* hbuf  = (float*)alloc((size_t)NNODE * 128 * 4);
    _Float16* xh = (_Float16*)alloc((size_t)NNODE * 128 * 2);
    _Float16* xl = (_Float16*)alloc((size_t)NNODE * 128 * 2);
    float* hg    = (float*)alloc(NGRAPH * 256 * 4);
    _Float16* wfh = (_Float16*)alloc(3 * 16384 * 2);
    _Float16* wfl = (_Float16*)alloc(3 * 16384 * 2);

    hipMemsetAsync(hg, 0, NGRAPH * 256 * 4, stream);
    k_wconv<<<192, 256, 0, stream>>>(Wl[0], Wl[1], Wl[2], wfh, wfl);
    k_csr<<<NGRAPH, 512, 0, stream>>>(srcE, dstE, rp, csr, gate, alive, dinv);

    const int rows_in[3] = {65536, 32768, 16384};
    const int Ks[3] = {256, 128, 64};
    const int Kp[3] = {512, 256, 128};
    for (int l = 0; l < 3; ++l) {
        k_gemm<<<rows_in[l] / 128, 256, 0, stream>>>(x_in, xh, xl, wfh + l * 16384, wfl + l * 16384,
                                                     gate, alive, hbuf, l == 0);
        k_agg<<<rows_in[l] / 8, 256, 0, stream>>>(hbuf, dinv, rp, csr, alive, bl[l], Pl[l],
                                                  xh, xl, score, Kp[l]);
        k_pool<<<NGRAPH, 512, 0, stream>>>(xh, xl, score, gate, alive, hg,
                                           rp, csr, dinv, Ks[l], l == 2);
    }
    k_mlp<<<NGRAPH, 256, 0, stream>>>(inp_c, hg, We, Wa, ba, Wb, bb, Wc, out);
}